// Round 19
// baseline (1706.537 us; speedup 1.0000x reference)
//
#include <hip/hip_runtime.h>
#include <hip/hip_bf16.h>
#include <math.h>

// Problem constants
constexpr int BB   = 8;
constexpr int NN   = 4096;
constexpr int MM   = 1024;
constexpr int KK   = 16;
constexpr int COUT = 128;
constexpr int NCBLK = 32;    // consumer blocks (128 waves); 216 CUs left EMPTY
#define RSQ 0.09f

__device__ __forceinline__ float dist2_exact(float ax, float ay, float az,
                                             float bx, float by, float bz) {
    // (a-b)^2 summed, no fma contraction: match numpy mul-then-add semantics
    float dx = __fsub_rn(ax, bx);
    float dy = __fsub_rn(ay, by);
    float dz = __fsub_rn(az, bz);
    return __fadd_rn(__fadd_rn(__fmul_rn(dx, dx), __fmul_rn(dy, dy)), __fmul_rn(dz, dz));
}

template<int CTRL>
__device__ __forceinline__ unsigned dpp_mov_u(unsigned v) {
    return (unsigned)__builtin_amdgcn_update_dpp((int)v, (int)v, CTRL, 0xF, 0xF, false);
}
__device__ __forceinline__ float readlane_f(float v, int j) {
    return __int_as_float(__builtin_amdgcn_readlane(__float_as_int(v), j));
}
__device__ __forceinline__ unsigned umax2(unsigned a, unsigned b) { return a > b ? a : b; }
__device__ __forceinline__ unsigned umin2(unsigned a, unsigned b) { return a < b ? a : b; }

// ---------------------------------------------------------------------------
// FUSED producer-consumer kernel.
//
// r18 -> r19 (single variable): consumer fleet 992 -> 128 waves (32 blocks);
// grid = 40, so 216 CUs hold NO blocks at all (vs 248 CUs of sleeping waves).
// Assignment follows global availability order s = m*8 + b (all producers
// publish a given m ~simultaneously): wave W takes s = W + 128k, k=0..63 ->
// distinct m spaced 16 (~11.7us arrival spacing > ~8us work, no pile-up),
// and the last 128 queries land on 128 distinct waves (tail ~8us).
// Producer (r13 FPS + relaxed publish) unchanged.
// ---------------------------------------------------------------------------
__global__ __launch_bounds__(256, 1) void fused_kernel(const float* __restrict__ x,
                                                       const float* __restrict__ pos,
                                                       const float* __restrict__ W1,
                                                       const float* __restrict__ b1,
                                                       const float* __restrict__ W2,
                                                       const float* __restrict__ b2,
                                                       const float* __restrict__ W3,
                                                       const float* __restrict__ b3,
                                                       unsigned* __restrict__ gsel,
                                                       float* __restrict__ out,
                                                       float* __restrict__ pos_s,
                                                       float* __restrict__ batch_s) {
    // producer LDS
    __shared__ float4 spos[NN];                       // 64 KB
    __shared__ int    shist[MM];                      // 4 KB
    __shared__ unsigned long long slotK[2][4];
    // consumer LDS
    __shared__ float sW2[64 * 64];                    // 16 KB
    __shared__ float sW3[64 * 128];                   // 32 KB
    __shared__ int   nslot[4][16];

    const int tid  = threadIdx.x;
    const int lane = tid & 63;
    const int wave = tid >> 6;

    if (blockIdx.x < BB) {
        // =================== PRODUCER: FPS (r13 verbatim) ===================
        const int b = blockIdx.x;
        const float* pb = pos + (size_t)b * NN * 3;

        for (int i = tid; i < NN; i += 256)
            spos[i] = make_float4(pb[i * 3 + 0], pb[i * 3 + 1], pb[i * 3 + 2], 0.0f);
        for (int i = tid; i < MM; i += 256)
            batch_s[(size_t)b * MM + i] = (float)b;
        if (tid == 0) {
            shist[0] = 0;
            __hip_atomic_store(&gsel[(size_t)b * MM], 1u, __ATOMIC_RELAXED,
                               __HIP_MEMORY_SCOPE_AGENT);   // m=0 -> point 0
        }
        if (tid < 8) slotK[tid >> 2][tid & 3] = 0ull;
        __syncthreads();

        float px[16], py[16], pz[16], d[16];
        const float4 p0 = spos[0];
#pragma unroll
        for (int k = 0; k < 16; k++) {
            float4 pt = spos[tid + k * 256];
            px[k] = pt.x; py[k] = pt.y; pz[k] = pt.z;
            d[k] = dist2_exact(pt.x, pt.y, pt.z, p0.x, p0.y, p0.z);
        }
        float bv;
        {
            float t1[8], t2[4];
#pragma unroll
            for (int k = 0; k < 8; k++) t1[k] = fmaxf(d[2 * k], d[2 * k + 1]);
#pragma unroll
            for (int k = 0; k < 4; k++) t2[k] = fmaxf(t1[2 * k], t1[2 * k + 1]);
            bv = fmaxf(fmaxf(t2[0], t2[1]), fmaxf(t2[2], t2[3]));
        }

        for (int m = 1; m < MM; m++) {
            const int par = m & 1;
            const unsigned tagm = (unsigned)m;

            const unsigned bvb = __float_as_uint(bv);

            unsigned rv = bvb;
            rv = umax2(rv, dpp_mov_u<0x111>(rv));
            rv = umax2(rv, dpp_mov_u<0x112>(rv));
            rv = umax2(rv, dpp_mov_u<0x114>(rv));
            rv = umax2(rv, dpp_mov_u<0x118>(rv));
            const unsigned r0 = (unsigned)__builtin_amdgcn_readlane((int)rv, 15);
            const unsigned r1 = (unsigned)__builtin_amdgcn_readlane((int)rv, 31);
            const unsigned r2 = (unsigned)__builtin_amdgcn_readlane((int)rv, 47);
            const unsigned r3 = (unsigned)__builtin_amdgcn_readlane((int)rv, 63);
            const unsigned vstar = umax2(umax2(r0, r1), umax2(r2, r3));

            unsigned kmask = 0u;
#pragma unroll
            for (int k = 0; k < 16; k++)
                kmask |= (d[k] == bv) ? (1u << k) : 0u;
            const unsigned bi = (unsigned)(tid + (__builtin_ctz(kmask) << 8));

            unsigned cand = (bvb == vstar) ? bi : 0xFFFFFFFFu;
            cand = umin2(cand, dpp_mov_u<0x111>(cand));
            cand = umin2(cand, dpp_mov_u<0x112>(cand));
            cand = umin2(cand, dpp_mov_u<0x114>(cand));
            cand = umin2(cand, dpp_mov_u<0x118>(cand));
            const unsigned c0 = (unsigned)__builtin_amdgcn_readlane((int)cand, 15);
            const unsigned c1 = (unsigned)__builtin_amdgcn_readlane((int)cand, 31);
            const unsigned c2 = (unsigned)__builtin_amdgcn_readlane((int)cand, 47);
            const unsigned c3 = (unsigned)__builtin_amdgcn_readlane((int)cand, 63);
            const unsigned wcand = umin2(umin2(c0, c1), umin2(c2, c3));

            if (lane == 0) {
                const unsigned long long key =
                    ((unsigned long long)vstar << 32)
                    | (unsigned long long)(((4095u - wcand) << 10) | tagm);
                __hip_atomic_store(&slotK[par][wave], key, __ATOMIC_RELAXED,
                                   __HIP_MEMORY_SCOPE_WORKGROUP);
            }

            unsigned long long k0, k1, k2, k3;
            for (;;) {
                k0 = __hip_atomic_load(&slotK[par][0], __ATOMIC_RELAXED, __HIP_MEMORY_SCOPE_WORKGROUP);
                k1 = __hip_atomic_load(&slotK[par][1], __ATOMIC_RELAXED, __HIP_MEMORY_SCOPE_WORKGROUP);
                k2 = __hip_atomic_load(&slotK[par][2], __ATOMIC_RELAXED, __HIP_MEMORY_SCOPE_WORKGROUP);
                k3 = __hip_atomic_load(&slotK[par][3], __ATOMIC_RELAXED, __HIP_MEMORY_SCOPE_WORKGROUP);
                bool ok = (((unsigned)k0 & 1023u) == tagm) &
                          (((unsigned)k1 & 1023u) == tagm) &
                          (((unsigned)k2 & 1023u) == tagm) &
                          (((unsigned)k3 & 1023u) == tagm);
                if (ok) break;
            }

            unsigned long long kA = (k0 > k1) ? k0 : k1;
            unsigned long long kB = (k2 > k3) ? k2 : k3;
            unsigned long long kk = (kA > kB) ? kA : kB;
            const int fi = 4095 - (int)(((unsigned)kk >> 10) & 4095u);

            if (tid == 0) {
                shist[m] = fi;
                // publish selection (fire-and-forget; nothing waits on vmcnt)
                __hip_atomic_store(&gsel[(size_t)b * MM + m], (unsigned)(fi + 1),
                                   __ATOMIC_RELAXED, __HIP_MEMORY_SCOPE_AGENT);
            }

            const float4 sp = spos[fi];
            if (m < MM - 1) {
#pragma unroll
                for (int k = 0; k < 16; k++) {
                    float nd = dist2_exact(px[k], py[k], pz[k], sp.x, sp.y, sp.z);
                    d[k] = fminf(d[k], nd);
                }
                float t1[8], t2[4];
#pragma unroll
                for (int k = 0; k < 8; k++) t1[k] = fmaxf(d[2 * k], d[2 * k + 1]);
#pragma unroll
                for (int k = 0; k < 4; k++) t2[k] = fmaxf(t1[2 * k], t1[2 * k + 1]);
                bv = fmaxf(fmaxf(t2[0], t2[1]), fmaxf(t2[2], t2[3]));
            }
        }

        __syncthreads();
        for (int i = tid; i < MM; i += 256) {
            float4 sp = spos[shist[i]];
            size_t o = (size_t)b * MM + i;
            pos_s[o * 3 + 0] = sp.x;
            pos_s[o * 3 + 1] = sp.y;
            pos_s[o * 3 + 2] = sp.z;
        }
        return;
    }

    // ===================== CONSUMER: radius + MLP =====================
    {
        const float4* s2 = (const float4*)W2;
        float4*       d2 = (float4*)sW2;
        for (int i = tid; i < 64 * 64 / 4; i += 256) d2[i] = s2[i];
        const float4* s3 = (const float4*)W3;
        float4*       d3 = (float4*)sW3;
        for (int i = tid; i < 64 * 128 / 4; i += 256) d3[i] = s3[i];
    }
    float w1c[6];
#pragma unroll
    for (int c = 0; c < 6; c++) w1c[c] = W1[c * 64 + lane];
    const float bb1  = b1[lane];
    const float bb2  = b2[lane];
    const float bb3a = b3[lane];
    const float bb3b = b3[64 + lane];
    __syncthreads();

    const int W = (blockIdx.x - BB) * 4 + wave;    // 0..127

    // wave W owns availability ranks s = W + 128k (s = m*8 + b): already in
    // publication order; distinct m spaced 16 (~11.7us) -> no pile-up; the
    // final 128 queries land on 128 distinct waves -> ~8us tail.
    for (int k = 0; k < 64; k++) {
        const int s = W + 128 * k;
        const int b = s & 7;
        const int m = s >> 3;
        const int q = b * MM + m;

        // ---- wait for this single query (one address, deep sleep) ----
        unsigned v = 0u;
        int guard = 0;
        for (;;) {
            v = __hip_atomic_load(&gsel[q], __ATOMIC_RELAXED,
                                  __HIP_MEMORY_SCOPE_AGENT);
            if (v >= 1u && v <= (unsigned)NN) break;
            if (++guard > 6000) break;             // ~20ms bound: fail loudly
            __builtin_amdgcn_s_sleep(127);         // ~8128 cyc =~ 3.4us idle
        }
        if (v == 0u || v > (unsigned)NN) continue;

        // ---------- process query q (r12 body; qpos from pos[]) ----------
        const int fi = (int)v - 1;
        const float qx = pos[((size_t)b * NN + fi) * 3 + 0];
        const float qy = pos[((size_t)b * NN + fi) * 3 + 1];
        const float qz = pos[((size_t)b * NN + fi) * 3 + 2];

        // radius scan: first-16 by index within RSQ (identical semantics)
        if (lane < 16) nslot[wave][lane] = 0;
        const float* pb = pos + (size_t)b * NN * 3;
        int cnt = 0;
        for (int c = 0; c < NN / 64; c++) {
            int p = c * 64 + lane;
            float px = pb[p * 3 + 0], py = pb[p * 3 + 1], pz = pb[p * 3 + 2];
            float d2 = dist2_exact(qx, qy, qz, px, py, pz);
            bool val = (d2 <= RSQ);
            unsigned long long msk = __ballot(val);
            if (val) {
                int rank = __popcll(msk & ((1ull << lane) - 1ull));
                int slot = cnt + rank;
                if (slot < KK) nslot[wave][slot] = p;
            }
            cnt += __popcll(msk);
            if (cnt >= KK) break;
        }
        const int cnt16 = min(cnt, KK);

        const int4 n0 = *(const int4*)&nslot[wave][0];
        const int4 n1 = *(const int4*)&nslot[wave][4];
        const int4 n2 = *(const int4*)&nslot[wave][8];
        const int4 n3 = *(const int4*)&nslot[wave][12];
        const int nidx[16] = { n0.x, n0.y, n0.z, n0.w, n1.x, n1.y, n1.z, n1.w,
                               n2.x, n2.y, n2.z, n2.w, n3.x, n3.y, n3.z, n3.w };

        // layer 1
        float h[17];
        unsigned vmask = 1u << 16;
#pragma unroll
        for (int e = 0; e < 16; e++) {
            const int p = (e < cnt16) ? nidx[e] : 0;
            const int g = b * NN + p;
            if ((e < cnt16) && (g != q)) vmask |= (1u << e);
            const float f0 = x[(size_t)g * 3 + 0];
            const float f1 = x[(size_t)g * 3 + 1];
            const float f2 = x[(size_t)g * 3 + 2];
            const float f3 = pos[(size_t)g * 3 + 0] - qx;
            const float f4 = pos[(size_t)g * 3 + 1] - qy;
            const float f5 = pos[(size_t)g * 3 + 2] - qz;
            float t = bb1 + f0 * w1c[0] + f1 * w1c[1] + f2 * w1c[2]
                          + f3 * w1c[3] + f4 * w1c[4] + f5 * w1c[5];
            h[e] = fmaxf(t, 0.0f);
        }
        {   // added self-loop (PyG numeric quirk)
            const int g = q;
            const float f0 = x[(size_t)g * 3 + 0];
            const float f1 = x[(size_t)g * 3 + 1];
            const float f2 = x[(size_t)g * 3 + 2];
            const float f3 = pos[(size_t)g * 3 + 0] - qx;
            const float f4 = pos[(size_t)g * 3 + 1] - qy;
            const float f5 = pos[(size_t)g * 3 + 2] - qz;
            float t = bb1 + f0 * w1c[0] + f1 * w1c[1] + f2 * w1c[2]
                          + f3 * w1c[3] + f4 * w1c[4] + f5 * w1c[5];
            h[16] = fmaxf(t, 0.0f);
        }

        // layer 2
        float acc[17];
#pragma unroll
        for (int e = 0; e < 17; e++) acc[e] = bb2;
#pragma unroll 2
        for (int j = 0; j < 64; j++) {
            const float wj = sW2[j * 64 + lane];
#pragma unroll
            for (int e = 0; e < 17; e++) {
                const float hj = readlane_f(h[e], j);
                acc[e] = __builtin_fmaf(hj, wj, acc[e]);
            }
        }
#pragma unroll
        for (int e = 0; e < 17; e++) h[e] = fmaxf(acc[e], 0.0f);

        // layer 3
        float a0[17], a1[17];
#pragma unroll
        for (int e = 0; e < 17; e++) { a0[e] = bb3a; a1[e] = bb3b; }
#pragma unroll 2
        for (int j = 0; j < 64; j++) {
            const float wa = sW3[j * 128 + lane];
            const float wb = sW3[j * 128 + 64 + lane];
#pragma unroll
            for (int e = 0; e < 17; e++) {
                const float hj = readlane_f(h[e], j);
                a0[e] = __builtin_fmaf(hj, wa, a0[e]);
                a1[e] = __builtin_fmaf(hj, wb, a1[e]);
            }
        }

        // masked max
        float m0 = -INFINITY, m1 = -INFINITY;
#pragma unroll
        for (int e = 0; e < 17; e++) {
            const bool vv = (vmask >> e) & 1u;
            m0 = vv ? fmaxf(m0, a0[e]) : m0;
            m1 = vv ? fmaxf(m1, a1[e]) : m1;
        }
        out[(size_t)q * COUT + lane]      = m0;
        out[(size_t)q * COUT + 64 + lane] = m1;
    }
}

// ---------------------------------------------------------------------------
extern "C" void kernel_launch(void* const* d_in, const int* in_sizes, int n_in,
                              void* d_out, int out_size, void* d_ws, size_t ws_size,
                              hipStream_t stream) {
    const float* x   = (const float*)d_in[0];
    const float* pos = (const float*)d_in[1];
    // d_in[2] = batch (unused: layout is implicit)
    const float* W1 = (const float*)d_in[3];
    const float* b1 = (const float*)d_in[4];
    const float* W2 = (const float*)d_in[5];
    const float* b2 = (const float*)d_in[6];
    const float* W3 = (const float*)d_in[7];
    const float* b3 = (const float*)d_in[8];

    float* outF    = (float*)d_out;
    float* out     = outF;                                  // [B*M, 128]
    float* pos_s   = outF + (size_t)BB * MM * COUT;         // [B*M, 3]
    float* batch_s = pos_s + (size_t)BB * MM * 3;           // [B*M]

    unsigned* gsel = (unsigned*)d_ws;                       // [B*M] selection index+1

    hipMemsetAsync(gsel, 0, (size_t)BB * MM * sizeof(unsigned), stream);

    fused_kernel<<<BB + NCBLK, 256, 0, stream>>>(x, pos, W1, b1, W2, b2, W3, b3,
                                                 gsel, out, pos_s, batch_s);
}

// Round 20
// 810.524 us; speedup vs baseline: 2.1055x; 2.1055x over previous
//
#include <hip/hip_runtime.h>
#include <hip/hip_bf16.h>
#include <math.h>

// Problem constants
constexpr int BB   = 8;
constexpr int NN   = 4096;
constexpr int MM   = 1024;
constexpr int KK   = 16;
constexpr int COUT = 128;
constexpr int NWRK = 992;    // worker waves: (256-8) blocks * 4 waves
#define RSQ 0.09f

__device__ __forceinline__ float dist2_exact(float ax, float ay, float az,
                                             float bx, float by, float bz) {
    // (a-b)^2 summed, no fma contraction: match numpy mul-then-add semantics
    float dx = __fsub_rn(ax, bx);
    float dy = __fsub_rn(ay, by);
    float dz = __fsub_rn(az, bz);
    return __fadd_rn(__fadd_rn(__fmul_rn(dx, dx), __fmul_rn(dy, dy)), __fmul_rn(dz, dz));
}

template<int CTRL>
__device__ __forceinline__ unsigned dpp_mov_u(unsigned v) {
    return (unsigned)__builtin_amdgcn_update_dpp((int)v, (int)v, CTRL, 0xF, 0xF, false);
}
__device__ __forceinline__ float readlane_f(float v, int j) {
    return __int_as_float(__builtin_amdgcn_readlane(__float_as_int(v), j));
}
__device__ __forceinline__ unsigned umax2(unsigned a, unsigned b) { return a > b ? a : b; }
__device__ __forceinline__ unsigned umin2(unsigned a, unsigned b) { return a < b ? a : b; }

// ---------------------------------------------------------------------------
// FUSED producer-consumer kernel — REVERT to the r18 state (809us total).
//
// r19 lesson (banked): the 248-block consumer fleet is LOAD-BEARING for the
// DVFS state. Shrinking it to 32 blocks dropped chip activity below the
// boost threshold and the producer fell to ~1.0GHz-effective (758 -> 1650us
// dispatch). The session-long "missing cycles" in the 8-CU FPS dispatches
// (r1-r4) were this same low-clock state; r13's split-kernel 702us benefited
// from the 2048-block mlp dispatch re-boosting the clock each replay.
// Moderate background (10-17% VALU) = sweet spot; saturated heater (r7)
// = power-limit throttle. Do not shrink or hot-spin the fleet.
// ---------------------------------------------------------------------------
__global__ __launch_bounds__(256, 1) void fused_kernel(const float* __restrict__ x,
                                                       const float* __restrict__ pos,
                                                       const float* __restrict__ W1,
                                                       const float* __restrict__ b1,
                                                       const float* __restrict__ W2,
                                                       const float* __restrict__ b2,
                                                       const float* __restrict__ W3,
                                                       const float* __restrict__ b3,
                                                       unsigned* __restrict__ gsel,
                                                       float* __restrict__ out,
                                                       float* __restrict__ pos_s,
                                                       float* __restrict__ batch_s) {
    // producer LDS
    __shared__ float4 spos[NN];                       // 64 KB
    __shared__ int    shist[MM];                      // 4 KB
    __shared__ unsigned long long slotK[2][4];
    // consumer LDS
    __shared__ float sW2[64 * 64];                    // 16 KB
    __shared__ float sW3[64 * 128];                   // 32 KB
    __shared__ int   nslot[4][16];

    const int tid  = threadIdx.x;
    const int lane = tid & 63;
    const int wave = tid >> 6;

    if (blockIdx.x < BB) {
        // =================== PRODUCER: FPS (r13 verbatim) ===================
        const int b = blockIdx.x;
        const float* pb = pos + (size_t)b * NN * 3;

        for (int i = tid; i < NN; i += 256)
            spos[i] = make_float4(pb[i * 3 + 0], pb[i * 3 + 1], pb[i * 3 + 2], 0.0f);
        for (int i = tid; i < MM; i += 256)
            batch_s[(size_t)b * MM + i] = (float)b;
        if (tid == 0) {
            shist[0] = 0;
            __hip_atomic_store(&gsel[(size_t)b * MM], 1u, __ATOMIC_RELAXED,
                               __HIP_MEMORY_SCOPE_AGENT);   // m=0 -> point 0
        }
        if (tid < 8) slotK[tid >> 2][tid & 3] = 0ull;
        __syncthreads();

        float px[16], py[16], pz[16], d[16];
        const float4 p0 = spos[0];
#pragma unroll
        for (int k = 0; k < 16; k++) {
            float4 pt = spos[tid + k * 256];
            px[k] = pt.x; py[k] = pt.y; pz[k] = pt.z;
            d[k] = dist2_exact(pt.x, pt.y, pt.z, p0.x, p0.y, p0.z);
        }
        float bv;
        {
            float t1[8], t2[4];
#pragma unroll
            for (int k = 0; k < 8; k++) t1[k] = fmaxf(d[2 * k], d[2 * k + 1]);
#pragma unroll
            for (int k = 0; k < 4; k++) t2[k] = fmaxf(t1[2 * k], t1[2 * k + 1]);
            bv = fmaxf(fmaxf(t2[0], t2[1]), fmaxf(t2[2], t2[3]));
        }

        for (int m = 1; m < MM; m++) {
            const int par = m & 1;
            const unsigned tagm = (unsigned)m;

            const unsigned bvb = __float_as_uint(bv);

            unsigned rv = bvb;
            rv = umax2(rv, dpp_mov_u<0x111>(rv));
            rv = umax2(rv, dpp_mov_u<0x112>(rv));
            rv = umax2(rv, dpp_mov_u<0x114>(rv));
            rv = umax2(rv, dpp_mov_u<0x118>(rv));
            const unsigned r0 = (unsigned)__builtin_amdgcn_readlane((int)rv, 15);
            const unsigned r1 = (unsigned)__builtin_amdgcn_readlane((int)rv, 31);
            const unsigned r2 = (unsigned)__builtin_amdgcn_readlane((int)rv, 47);
            const unsigned r3 = (unsigned)__builtin_amdgcn_readlane((int)rv, 63);
            const unsigned vstar = umax2(umax2(r0, r1), umax2(r2, r3));

            unsigned kmask = 0u;
#pragma unroll
            for (int k = 0; k < 16; k++)
                kmask |= (d[k] == bv) ? (1u << k) : 0u;
            const unsigned bi = (unsigned)(tid + (__builtin_ctz(kmask) << 8));

            unsigned cand = (bvb == vstar) ? bi : 0xFFFFFFFFu;
            cand = umin2(cand, dpp_mov_u<0x111>(cand));
            cand = umin2(cand, dpp_mov_u<0x112>(cand));
            cand = umin2(cand, dpp_mov_u<0x114>(cand));
            cand = umin2(cand, dpp_mov_u<0x118>(cand));
            const unsigned c0 = (unsigned)__builtin_amdgcn_readlane((int)cand, 15);
            const unsigned c1 = (unsigned)__builtin_amdgcn_readlane((int)cand, 31);
            const unsigned c2 = (unsigned)__builtin_amdgcn_readlane((int)cand, 47);
            const unsigned c3 = (unsigned)__builtin_amdgcn_readlane((int)cand, 63);
            const unsigned wcand = umin2(umin2(c0, c1), umin2(c2, c3));

            if (lane == 0) {
                const unsigned long long key =
                    ((unsigned long long)vstar << 32)
                    | (unsigned long long)(((4095u - wcand) << 10) | tagm);
                __hip_atomic_store(&slotK[par][wave], key, __ATOMIC_RELAXED,
                                   __HIP_MEMORY_SCOPE_WORKGROUP);
            }

            unsigned long long k0, k1, k2, k3;
            for (;;) {
                k0 = __hip_atomic_load(&slotK[par][0], __ATOMIC_RELAXED, __HIP_MEMORY_SCOPE_WORKGROUP);
                k1 = __hip_atomic_load(&slotK[par][1], __ATOMIC_RELAXED, __HIP_MEMORY_SCOPE_WORKGROUP);
                k2 = __hip_atomic_load(&slotK[par][2], __ATOMIC_RELAXED, __HIP_MEMORY_SCOPE_WORKGROUP);
                k3 = __hip_atomic_load(&slotK[par][3], __ATOMIC_RELAXED, __HIP_MEMORY_SCOPE_WORKGROUP);
                bool ok = (((unsigned)k0 & 1023u) == tagm) &
                          (((unsigned)k1 & 1023u) == tagm) &
                          (((unsigned)k2 & 1023u) == tagm) &
                          (((unsigned)k3 & 1023u) == tagm);
                if (ok) break;
            }

            unsigned long long kA = (k0 > k1) ? k0 : k1;
            unsigned long long kB = (k2 > k3) ? k2 : k3;
            unsigned long long kk = (kA > kB) ? kA : kB;
            const int fi = 4095 - (int)(((unsigned)kk >> 10) & 4095u);

            if (tid == 0) {
                shist[m] = fi;
                // publish selection (fire-and-forget; nothing waits on vmcnt)
                __hip_atomic_store(&gsel[(size_t)b * MM + m], (unsigned)(fi + 1),
                                   __ATOMIC_RELAXED, __HIP_MEMORY_SCOPE_AGENT);
            }

            const float4 sp = spos[fi];
            if (m < MM - 1) {
#pragma unroll
                for (int k = 0; k < 16; k++) {
                    float nd = dist2_exact(px[k], py[k], pz[k], sp.x, sp.y, sp.z);
                    d[k] = fminf(d[k], nd);
                }
                float t1[8], t2[4];
#pragma unroll
                for (int k = 0; k < 8; k++) t1[k] = fmaxf(d[2 * k], d[2 * k + 1]);
#pragma unroll
                for (int k = 0; k < 4; k++) t2[k] = fmaxf(t1[2 * k], t1[2 * k + 1]);
                bv = fmaxf(fmaxf(t2[0], t2[1]), fmaxf(t2[2], t2[3]));
            }
        }

        __syncthreads();
        for (int i = tid; i < MM; i += 256) {
            float4 sp = spos[shist[i]];
            size_t o = (size_t)b * MM + i;
            pos_s[o * 3 + 0] = sp.x;
            pos_s[o * 3 + 1] = sp.y;
            pos_s[o * 3 + 2] = sp.z;
        }
        return;
    }

    // ===================== CONSUMER: radius + MLP =====================
    {
        const float4* s2 = (const float4*)W2;
        float4*       d2 = (float4*)sW2;
        for (int i = tid; i < 64 * 64 / 4; i += 256) d2[i] = s2[i];
        const float4* s3 = (const float4*)W3;
        float4*       d3 = (float4*)sW3;
        for (int i = tid; i < 64 * 128 / 4; i += 256) d3[i] = s3[i];
    }
    float w1c[6];
#pragma unroll
    for (int c = 0; c < 6; c++) w1c[c] = W1[c * 64 + lane];
    const float bb1  = b1[lane];
    const float bb2  = b2[lane];
    const float bb3a = b3[lane];
    const float bb3b = b3[64 + lane];
    __syncthreads();

    const int W = (blockIdx.x - BB) * 4 + wave;    // 0..991

    // collect this wave's queries and sort by m = q & 1023 (availability order)
    int myq[9]; int nq = 0;
#pragma unroll
    for (int k = 0; k < 9; k++) {
        int q = W + NWRK * k;
        if (q < BB * MM) myq[nq++] = q;
    }
    for (int i = 1; i < nq; i++) {                 // insertion sort (<=9 elems)
        int v = myq[i]; int j = i - 1;
        while (j >= 0 && (myq[j] & 1023) > (v & 1023)) { myq[j + 1] = myq[j]; j--; }
        myq[j + 1] = v;
    }

    for (int i = 0; i < nq; i++) {
        const int q = myq[i];

        // ---- wait for this single query (one address, deep sleep) ----
        unsigned v = 0u;
        int guard = 0;
        for (;;) {
            v = __hip_atomic_load(&gsel[q], __ATOMIC_RELAXED,
                                  __HIP_MEMORY_SCOPE_AGENT);
            if (v >= 1u && v <= (unsigned)NN) break;
            if (++guard > 6000) break;             // ~20ms bound: fail loudly
            __builtin_amdgcn_s_sleep(127);         // ~8128 cyc =~ 3.4us idle
        }
        if (v == 0u || v > (unsigned)NN) continue;

        // ---------- process query q (r12 body; qpos from pos[]) ----------
        const int b  = q >> 10;
        const int fi = (int)v - 1;
        const float qx = pos[((size_t)b * NN + fi) * 3 + 0];
        const float qy = pos[((size_t)b * NN + fi) * 3 + 1];
        const float qz = pos[((size_t)b * NN + fi) * 3 + 2];

        // radius scan: first-16 by index within RSQ (identical semantics)
        if (lane < 16) nslot[wave][lane] = 0;
        const float* pb = pos + (size_t)b * NN * 3;
        int cnt = 0;
        for (int c = 0; c < NN / 64; c++) {
            int p = c * 64 + lane;
            float px = pb[p * 3 + 0], py = pb[p * 3 + 1], pz = pb[p * 3 + 2];
            float d2 = dist2_exact(qx, qy, qz, px, py, pz);
            bool val = (d2 <= RSQ);
            unsigned long long msk = __ballot(val);
            if (val) {
                int rank = __popcll(msk & ((1ull << lane) - 1ull));
                int slot = cnt + rank;
                if (slot < KK) nslot[wave][slot] = p;
            }
            cnt += __popcll(msk);
            if (cnt >= KK) break;
        }
        const int cnt16 = min(cnt, KK);

        const int4 n0 = *(const int4*)&nslot[wave][0];
        const int4 n1 = *(const int4*)&nslot[wave][4];
        const int4 n2 = *(const int4*)&nslot[wave][8];
        const int4 n3 = *(const int4*)&nslot[wave][12];
        const int nidx[16] = { n0.x, n0.y, n0.z, n0.w, n1.x, n1.y, n1.z, n1.w,
                               n2.x, n2.y, n2.z, n2.w, n3.x, n3.y, n3.z, n3.w };

        // layer 1
        float h[17];
        unsigned vmask = 1u << 16;
#pragma unroll
        for (int e = 0; e < 16; e++) {
            const int p = (e < cnt16) ? nidx[e] : 0;
            const int g = b * NN + p;
            if ((e < cnt16) && (g != q)) vmask |= (1u << e);
            const float f0 = x[(size_t)g * 3 + 0];
            const float f1 = x[(size_t)g * 3 + 1];
            const float f2 = x[(size_t)g * 3 + 2];
            const float f3 = pos[(size_t)g * 3 + 0] - qx;
            const float f4 = pos[(size_t)g * 3 + 1] - qy;
            const float f5 = pos[(size_t)g * 3 + 2] - qz;
            float t = bb1 + f0 * w1c[0] + f1 * w1c[1] + f2 * w1c[2]
                          + f3 * w1c[3] + f4 * w1c[4] + f5 * w1c[5];
            h[e] = fmaxf(t, 0.0f);
        }
        {   // added self-loop (PyG numeric quirk)
            const int g = q;
            const float f0 = x[(size_t)g * 3 + 0];
            const float f1 = x[(size_t)g * 3 + 1];
            const float f2 = x[(size_t)g * 3 + 2];
            const float f3 = pos[(size_t)g * 3 + 0] - qx;
            const float f4 = pos[(size_t)g * 3 + 1] - qy;
            const float f5 = pos[(size_t)g * 3 + 2] - qz;
            float t = bb1 + f0 * w1c[0] + f1 * w1c[1] + f2 * w1c[2]
                          + f3 * w1c[3] + f4 * w1c[4] + f5 * w1c[5];
            h[16] = fmaxf(t, 0.0f);
        }

        // layer 2
        float acc[17];
#pragma unroll
        for (int e = 0; e < 17; e++) acc[e] = bb2;
#pragma unroll 2
        for (int j = 0; j < 64; j++) {
            const float wj = sW2[j * 64 + lane];
#pragma unroll
            for (int e = 0; e < 17; e++) {
                const float hj = readlane_f(h[e], j);
                acc[e] = __builtin_fmaf(hj, wj, acc[e]);
            }
        }
#pragma unroll
        for (int e = 0; e < 17; e++) h[e] = fmaxf(acc[e], 0.0f);

        // layer 3
        float a0[17], a1[17];
#pragma unroll
        for (int e = 0; e < 17; e++) { a0[e] = bb3a; a1[e] = bb3b; }
#pragma unroll 2
        for (int j = 0; j < 64; j++) {
            const float wa = sW3[j * 128 + lane];
            const float wb = sW3[j * 128 + 64 + lane];
#pragma unroll
            for (int e = 0; e < 17; e++) {
                const float hj = readlane_f(h[e], j);
                a0[e] = __builtin_fmaf(hj, wa, a0[e]);
                a1[e] = __builtin_fmaf(hj, wb, a1[e]);
            }
        }

        // masked max
        float m0 = -INFINITY, m1 = -INFINITY;
#pragma unroll
        for (int e = 0; e < 17; e++) {
            const bool vv = (vmask >> e) & 1u;
            m0 = vv ? fmaxf(m0, a0[e]) : m0;
            m1 = vv ? fmaxf(m1, a1[e]) : m1;
        }
        out[(size_t)q * COUT + lane]      = m0;
        out[(size_t)q * COUT + 64 + lane] = m1;
    }
}

// ---------------------------------------------------------------------------
extern "C" void kernel_launch(void* const* d_in, const int* in_sizes, int n_in,
                              void* d_out, int out_size, void* d_ws, size_t ws_size,
                              hipStream_t stream) {
    const float* x   = (const float*)d_in[0];
    const float* pos = (const float*)d_in[1];
    // d_in[2] = batch (unused: layout is implicit)
    const float* W1 = (const float*)d_in[3];
    const float* b1 = (const float*)d_in[4];
    const float* W2 = (const float*)d_in[5];
    const float* b2 = (const float*)d_in[6];
    const float* W3 = (const float*)d_in[7];
    const float* b3 = (const float*)d_in[8];

    float* outF    = (float*)d_out;
    float* out     = outF;                                  // [B*M, 128]
    float* pos_s   = outF + (size_t)BB * MM * COUT;         // [B*M, 3]
    float* batch_s = pos_s + (size_t)BB * MM * 3;           // [B*M]

    unsigned* gsel = (unsigned*)d_ws;                       // [B*M] selection index+1

    hipMemsetAsync(gsel, 0, (size_t)BB * MM * sizeof(unsigned), stream);

    fused_kernel<<<256, 256, 0, stream>>>(x, pos, W1, b1, W2, b2, W3, b3,
                                          gsel, out, pos_s, batch_s);
}